// Round 12
// baseline (45.867 us; speedup 1.0000x reference)
//
#include <hip/hip_runtime.h>

#define BB 2
#define TT 512
#define HH 256
#define NBT (BB * TT)          // 1024

#define C2LOG2E 2.8853900817779268f   // 2*log2(e): exp(2x)=2^(C*x)
#define LOG2E   1.4426950408889634f

// ---------------------------------------------------------------------------
// Kernel 0 (prep_T): transpose Wq,Wk -> WT[h][o] fp32 (R6's proven tile code).
// grid 32: blocks 0..15 Wq (16 64x64 tiles), 16..31 Wk.
// ---------------------------------------------------------------------------
__global__ __launch_bounds__(256) void prep_T(
    const float* __restrict__ Wq, const float* __restrict__ Wk,
    float* __restrict__ WqT, float* __restrict__ WkT)
{
    int bid = blockIdx.x;
    int tid = threadIdx.x;
    const float* W = (bid < 16) ? Wq : Wk;
    float* WT = (bid < 16) ? WqT : WkT;
    int tile = bid & 15;
    int o0 = (tile >> 2) * 64, h0 = (tile & 3) * 64;
    __shared__ float t_sh[64][65];
    int ty = tid >> 6, tx = tid & 63;
#pragma unroll
    for (int r = 0; r < 16; ++r) {
        int o = r * 4 + ty;
        t_sh[o][tx] = W[(o0 + o) * HH + h0 + tx];
    }
    __syncthreads();
#pragma unroll
    for (int r = 0; r < 16; ++r) {
        int h = r * 4 + ty;
        WT[(h0 + h) * HH + o0 + tx] = t_sh[tx][h];
    }
}

// ---------------------------------------------------------------------------
// Kernel 1 (proj_outer): Y = exp2(C * X @ W^T) as VALU outer-product.
// Grid 256 x 256thr (4 waves). Block = 8 bt-rows x all 256 o.
// Wave wv owns o-slice [wv*64, wv*64+64), lane = o within slice.
// - X staged to LDS coalesced, read as uniform broadcasts (f4 per r).
// - WT[h][o] loads: 64 lanes x 4B contiguous = 256B coalesced.
// - Eq stores: 256B/wave coalesced.  EkT: per-wave LDS bounce -> 128B chunks.
// No MFMA, no scatter, no serial wave-uniform global loads.
// ---------------------------------------------------------------------------
__global__ __launch_bounds__(256) void proj_outer(
    const float* __restrict__ Q, const float* __restrict__ K,
    const float* __restrict__ WqT, const float* __restrict__ WkT,
    float* __restrict__ Eq, float* __restrict__ EkT)
{
    __shared__ float x_sh[8][HH];          // 8 KB
    __shared__ float ek_sh[4][8][68];      // 8.5 KB (K-half bounce, pad 68)

    int bid = blockIdx.x;                  // 0..255
    bool isK = (bid >= 128);
    int bt0 = (bid & 127) * 8;
    const float* X = isK ? K : Q;
    const float* WT = isK ? WkT : WqT;
    int tid = threadIdx.x;
    int wv = tid >> 6, lane = tid & 63;
    int o = wv * 64 + lane;

    // ---- stage 8 X rows, coalesced (each pass: 4 rows, 64 f4/row) ----
#pragma unroll
    for (int p = 0; p < 2; ++p) {
        int fi = p * 256 + tid;            // f4 index 0..511
        int r = fi >> 6, c = fi & 63;
        *reinterpret_cast<float4*>(&x_sh[r][c * 4]) =
            *reinterpret_cast<const float4*>(X + (bt0 + r) * HH + c * 4);
    }
    __syncthreads();

    // ---- outer-product accumulation ----
    float acc[8] = {0.f, 0.f, 0.f, 0.f, 0.f, 0.f, 0.f, 0.f};
    const float* wcol = WT + o;            // WT[h*HH + o]
#pragma unroll 2
    for (int h4 = 0; h4 < 64; ++h4) {
        float w0 = wcol[(h4 * 4 + 0) * HH];
        float w1 = wcol[(h4 * 4 + 1) * HH];
        float w2 = wcol[(h4 * 4 + 2) * HH];
        float w3 = wcol[(h4 * 4 + 3) * HH];
#pragma unroll
        for (int r = 0; r < 8; ++r) {
            float4 x4 = *reinterpret_cast<const float4*>(&x_sh[r][h4 * 4]);
            float a = acc[r];
            a = __builtin_fmaf(x4.x, w0, a);
            a = __builtin_fmaf(x4.y, w1, a);
            a = __builtin_fmaf(x4.z, w2, a);
            a = __builtin_fmaf(x4.w, w3, a);
            acc[r] = a;
        }
    }

    float e[8];
#pragma unroll
    for (int r = 0; r < 8; ++r)
        e[r] = __builtin_amdgcn_exp2f(acc[r] * C2LOG2E);

    if (!isK) {
#pragma unroll
        for (int r = 0; r < 8; ++r)
            Eq[(bt0 + r) * HH + o] = e[r];            // 256B/wave coalesced
    } else {
        // bounce: ek_sh[wv][r][lane] = e[r]; then 2 passes of f4 writes,
        // 8 consecutive lanes (r fast) -> 128B contiguous per slab.
#pragma unroll
        for (int r = 0; r < 8; ++r)
            ek_sh[wv][r][lane] = e[r];
        // same wave reads its own region; compiler inserts lgkmcnt wait
#pragma unroll
        for (int p = 0; p < 2; ++p) {
            int id = p * 64 + lane;        // 0..127
            int s = id >> 3, r = id & 7;   // slab 0..15, row 0..7
            float4 val = *reinterpret_cast<const float4*>(&ek_sh[wv][r][s * 4]);
            *reinterpret_cast<float4*>(
                EkT + ((wv * 16 + s) * NBT + bt0 + r) * 4) = val;
        }
    }
}

// ---------------------------------------------------------------------------
// Kernel 2 (attn): unchanged (measured ~5.8us).
// scores via rcp(Eq*Ek+1) + sum-only softmax + fp32 K context.
// ---------------------------------------------------------------------------
__global__ __launch_bounds__(512, 8) void attn_kernel(
    const float* __restrict__ Eq, const float* __restrict__ EkT,
    const float* __restrict__ Kraw, const float* __restrict__ v,
    float* __restrict__ ctx, float* __restrict__ alpha)
{
    __shared__ float eq_sh[HH];
    __shared__ float v2_sh[HH];
    __shared__ float al_sh[TT];
    __shared__ float red[8];
    __shared__ float4 cred[8][64];

    int bt = blockIdx.x;
    int b = bt / TT;
    int idx = bt % TT;
    int t = (idx < 256) ? idx : 767 - idx;
    int btr = b * TT + t;
    int tid = threadIdx.x;

    if (tid < HH) {
        eq_sh[tid] = Eq[btr * HH + tid];
        v2_sh[tid] = -2.0f * v[tid];
    }
    __syncthreads();

    // ---- score for s = tid (coalesced EkT loads: lanes contiguous) ----
    float sc = 0.f;
    if (tid <= t) {
        const float4* ek = reinterpret_cast<const float4*>(EkT) + (b * TT + tid);
        const float4* q4p = reinterpret_cast<const float4*>(eq_sh);
        const float4* v4p = reinterpret_cast<const float4*>(v2_sh);
#pragma unroll 4
        for (int h4 = 0; h4 < HH / 4; ++h4) {
            float4 e4 = ek[h4 * NBT];     // 1KB/wave
            float4 q4 = q4p[h4];          // broadcast
            float4 vv = v4p[h4];          // broadcast
            float r0 = __builtin_amdgcn_rcpf(__builtin_fmaf(q4.x, e4.x, 1.f));
            float r1 = __builtin_amdgcn_rcpf(__builtin_fmaf(q4.y, e4.y, 1.f));
            float r2 = __builtin_amdgcn_rcpf(__builtin_fmaf(q4.z, e4.z, 1.f));
            float r3 = __builtin_amdgcn_rcpf(__builtin_fmaf(q4.w, e4.w, 1.f));
            sc = __builtin_fmaf(vv.x, r0, sc);
            sc = __builtin_fmaf(vv.y, r1, sc);
            sc = __builtin_fmaf(vv.z, r2, sc);
            sc = __builtin_fmaf(vv.w, r3, sc);
        }
    }

    // ---- softmax: sum only (scores bounded by 2*sum|v| ~ 26) ----
    float e = (tid <= t) ? __builtin_amdgcn_exp2f(sc * LOG2E) : 0.f;
    float ssum = e;
#pragma unroll
    for (int off = 32; off > 0; off >>= 1)
        ssum += __shfl_xor(ssum, off);
    if ((tid & 63) == 0) red[tid >> 6] = ssum;
    __syncthreads();
    float denom = (red[0] + red[1]) + (red[2] + red[3])
                + (red[4] + red[5]) + (red[6] + red[7]);
    float a0 = e * __builtin_amdgcn_rcpf(denom);

    al_sh[tid] = a0;
    alpha[btr * TT + tid] = a0;
    __syncthreads();

    // ---- context: hc = tid&63 (4 channels), sg = tid>>6 (s-stride 8) ----
    int hc = tid & 63, sg = tid >> 6;
    const float4* kb4 = reinterpret_cast<const float4*>(Kraw + b * TT * HH) + hc;
    float4 acc4 = {0.f, 0.f, 0.f, 0.f};
    for (int s = sg; s <= t; s += 8) {
        float4 k4 = kb4[s * 64];             // coalesced 1KB/wave
        float  al = al_sh[s];                // wave-uniform broadcast
        acc4.x = __builtin_fmaf(al, k4.x, acc4.x);
        acc4.y = __builtin_fmaf(al, k4.y, acc4.y);
        acc4.z = __builtin_fmaf(al, k4.z, acc4.z);
        acc4.w = __builtin_fmaf(al, k4.w, acc4.w);
    }
    cred[sg][hc] = acc4;
    __syncthreads();
    if (sg == 0) {
        float4 out = {0.f, 0.f, 0.f, 0.f};
#pragma unroll
        for (int g = 0; g < 8; ++g) {
            float4 cc = cred[g][hc];
            out.x += cc.x; out.y += cc.y; out.z += cc.z; out.w += cc.w;
        }
        reinterpret_cast<float4*>(ctx + btr * HH)[hc] = out;
    }
}

extern "C" void kernel_launch(void* const* d_in, const int* in_sizes, int n_in,
                              void* d_out, int out_size, void* d_ws, size_t ws_size,
                              hipStream_t stream) {
    const float* Q  = (const float*)d_in[0];
    const float* K  = (const float*)d_in[1];
    const float* Wq = (const float*)d_in[2];
    const float* Wk = (const float*)d_in[3];
    const float* v  = (const float*)d_in[4];

    float* ctx   = (float*)d_out;                      // B*T*H
    float* alpha = (float*)d_out + NBT * HH;           // B*T*T

    // ws: Eq | EkT | WqT | WkT  (all fp32)
    float* Eq  = (float*)d_ws;                         // NBT*HH (1 MB)
    float* EkT = Eq + NBT * HH;                        // NBT*HH (1 MB)
    float* WqT = EkT + NBT * HH;                       // HH*HH (256 KB)
    float* WkT = WqT + HH * HH;                        // HH*HH (256 KB)

    prep_T<<<32, 256, 0, stream>>>(Wq, Wk, WqT, WkT);
    proj_outer<<<256, 256, 0, stream>>>(Q, K, WqT, WkT, Eq, EkT);
    attn_kernel<<<NBT, 512, 0, stream>>>(Eq, EkT, K, v, ctx, alpha);
}